// Round 1
// baseline (4163.438 us; speedup 1.0000x reference)
//
#include <hip/hip_runtime.h>

// Average-trace constant from the Python module (length 120).
__device__ __constant__ float AVG_D[120] = {
    0.0256f,0.0823f,0.1157f,0.1315f,0.1366f,0.1369f,0.1347f,0.1308f,0.1259f,0.1205f,
    0.1146f,0.1086f,0.1028f,0.0970f,0.0913f,0.0858f,0.0805f,0.0756f,0.0708f,0.0664f,
    0.0623f,0.0584f,0.0549f,0.0515f,0.0485f,0.0456f,0.0429f,0.0404f,0.0381f,0.0360f,
    0.0340f,0.0321f,0.0304f,0.0287f,0.0272f,0.0258f,0.0245f,0.0233f,0.0222f,0.0211f,
    0.0201f,0.0191f,0.0182f,0.0173f,0.0165f,0.0158f,0.0150f,0.0143f,0.0137f,0.0130f,
    0.0125f,0.0119f,0.0114f,0.0108f,0.0104f,0.0099f,0.0095f,0.0091f,0.0087f,0.0083f,
    0.0080f,0.0077f,0.0074f,0.0071f,0.0068f,0.0065f,0.0062f,0.0060f,0.0058f,0.0055f,
    0.0053f,0.0050f,0.0049f,0.0047f,0.0045f,0.0044f,0.0042f,0.0040f,0.0039f,0.0038f,
    0.0036f,0.0034f,0.0033f,0.0032f,0.0031f,0.0030f,0.0029f,0.0028f,0.0027f,0.0026f,
    0.0025f,0.0024f,0.0023f,0.0022f,0.0021f,0.0021f,0.0020f,0.0019f,0.0018f,0.0018f,
    0.0017f,0.0017f,0.0016f,0.0016f,0.0015f,0.0015f,0.0014f,0.0014f,0.0013f,0.0013f,
    0.0013f,0.0012f,0.0012f,0.0011f,0.0011f,0.0011f,0.0010f,0.0010f,0.0010f,0.0009f
};

__device__ __forceinline__ float sigf(float x) {
    // 1/(1+exp(-x)); v_exp + v_rcp, graceful at extremes (rcp(inf)=0)
    return __builtin_amdgcn_rcpf(1.0f + __expf(-x));
}
__device__ __forceinline__ float tanh_fast(float x) {
    // 2*sigmoid(2x)-1
    return fmaf(2.0f, __builtin_amdgcn_rcpf(1.0f + __expf(-2.0f * x)), -1.0f);
}

// 2 lanes per sequence: lane half=0 owns hidden units 0..14, half=1 owns 15..29.
// Block = 256 threads = 128 sequences. Grid = 256 blocks (N=32768).
__global__ __launch_bounds__(256, 1)
void lstm_trace_kernel(const float* __restrict__ feat,    // [N,12]
                       const float* __restrict__ w_ih1,   // [120,13]
                       const float* __restrict__ w_hh1,   // [120,30]
                       const float* __restrict__ b1,      // [120]
                       const float* __restrict__ w_ih2,   // [4,30]
                       const float* __restrict__ w_hh2,   // [4]
                       const float* __restrict__ b2,      // [4]
                       float* __restrict__ out)           // [N,120]
{
    // W_hh1 repacked as [unit u][j][gate q] so one ds_read_b128 feeds 4 FMAs.
    __shared__ float4 w4_s[30 * 30];        // 14.4 KB
    __shared__ float4 wih2_s[30];           // [j][gate]  480 B
    __shared__ float  wih1_s[120 * 13];     // 6.24 KB
    __shared__ float  b1_s[120];
    __shared__ __align__(16) float out_s[128 * 120];  // 61.44 KB

    const int tid = threadIdx.x;

    {
        float* w4f = reinterpret_cast<float*>(w4_s);
        for (int i = tid; i < 3600; i += 256) {
            int q = i & 3, r = i >> 2;
            int j = r % 30, u = r / 30;
            w4f[i] = w_hh1[(q * 30 + u) * 30 + j];
        }
        float* w2f = reinterpret_cast<float*>(wih2_s);
        if (tid < 120) {
            int q = tid & 3, j = tid >> 2;
            w2f[tid] = w_ih2[q * 30 + j];
        }
        for (int i = tid; i < 120 * 13; i += 256) wih1_s[i] = w_ih1[i];
        if (tid < 120) b1_s[tid] = b1[tid];
    }
    __syncthreads();

    const int gtid = blockIdx.x * 256 + tid;
    const int seq  = gtid >> 1;
    const int half = gtid & 1;
    const int ub   = half * 15;       // first unit owned by this lane
    const int sloc = tid >> 1;        // 0..127 local sequence slot

    // Per-sequence constant input projections (avg column kept separate).
    float f[12];
#pragma unroll
    for (int d = 0; d < 12; d++) f[d] = feat[seq * 12 + d];

    float projb[60], wcol[60];
#pragma unroll
    for (int k = 0; k < 15; k++) {
#pragma unroll
        for (int q = 0; q < 4; q++) {
            int r = q * 30 + ub + k;
            float acc = b1_s[r];
#pragma unroll
            for (int d = 0; d < 12; d++) acc = fmaf(f[d], wih1_s[r * 13 + d], acc);
            projb[k * 4 + q] = acc;
            wcol[k * 4 + q]  = wih1_s[r * 13 + 12];
        }
    }

    float h[30], c[15];
#pragma unroll
    for (int j = 0; j < 30; j++) h[j] = 0.0f;
#pragma unroll
    for (int k = 0; k < 15; k++) c[k] = 0.0f;
    float h2 = 0.0f, c2 = 0.0f;
    const float wh2[4] = { w_hh2[0], w_hh2[1], w_hh2[2], w_hh2[3] };
    const float bb2[4] = { b2[0], b2[1], b2[2], b2[3] };

#pragma unroll 1
    for (int t = 0; t < 120; t++) {
        const float at = AVG_D[t];
        float hn[15];

#pragma unroll
        for (int k = 0; k < 15; k++) {
            float ai = fmaf(at, wcol[k * 4 + 0], projb[k * 4 + 0]);
            float af = fmaf(at, wcol[k * 4 + 1], projb[k * 4 + 1]);
            float ag = fmaf(at, wcol[k * 4 + 2], projb[k * 4 + 2]);
            float ao = fmaf(at, wcol[k * 4 + 3], projb[k * 4 + 3]);
            const int u = ub + k;
#pragma unroll
            for (int j = 0; j < 30; j++) {
                const float4 w = w4_s[u * 30 + j];
                ai = fmaf(h[j], w.x, ai);
                af = fmaf(h[j], w.y, af);
                ag = fmaf(h[j], w.z, ag);
                ao = fmaf(h[j], w.w, ao);
            }
            const float ck = sigf(af) * c[k] + sigf(ai) * tanh_fast(ag);
            c[k]  = ck;
            hn[k] = sigf(ao) * tanh_fast(ck);
        }

        // LSTM2 (hidden=1): per-lane partial dot over owned 15 units, butterfly.
        float p0 = 0.0f, p1 = 0.0f, p2 = 0.0f, p3 = 0.0f;
#pragma unroll
        for (int k = 0; k < 15; k++) {
            const float4 w2 = wih2_s[ub + k];
            p0 = fmaf(hn[k], w2.x, p0);
            p1 = fmaf(hn[k], w2.y, p1);
            p2 = fmaf(hn[k], w2.z, p2);
            p3 = fmaf(hn[k], w2.w, p3);
        }
        p0 += __shfl_xor(p0, 1);
        p1 += __shfl_xor(p1, 1);
        p2 += __shfl_xor(p2, 1);
        p3 += __shfl_xor(p3, 1);

        const float gi = p0 + fmaf(h2, wh2[0], bb2[0]);
        const float gf = p1 + fmaf(h2, wh2[1], bb2[1]);
        const float gg = p2 + fmaf(h2, wh2[2], bb2[2]);
        const float go = p3 + fmaf(h2, wh2[3], bb2[3]);
        c2 = sigf(gf) * c2 + sigf(gi) * tanh_fast(gg);
        h2 = sigf(go) * tanh_fast(c2);

        if (half == 0) out_s[sloc * 120 + t] = h2;

        // Exchange halves of the new hidden state for the next step.
#pragma unroll
        for (int m = 0; m < 15; m++) {
            const float oth = __shfl_xor(hn[m], 1);
            h[m]      = half ? oth   : hn[m];
            h[m + 15] = half ? hn[m] : oth;
        }
    }

    __syncthreads();
    // Coalesced flush: 128 seqs x 120 t = 3840 float4s, 15 per thread.
    float* outb = out + (size_t)blockIdx.x * 128 * 120;
#pragma unroll
    for (int it = 0; it < 15; it++) {
        const int fidx = it * 256 + tid;
        const int s = fidx / 30, j = fidx % 30;
        const float4 v = *reinterpret_cast<const float4*>(&out_s[s * 120 + j * 4]);
        *reinterpret_cast<float4*>(&outb[s * 120 + j * 4]) = v;
    }
}

extern "C" void kernel_launch(void* const* d_in, const int* in_sizes, int n_in,
                              void* d_out, int out_size, void* d_ws, size_t ws_size,
                              hipStream_t stream) {
    (void)in_sizes; (void)n_in; (void)out_size; (void)d_ws; (void)ws_size;
    const float* feat  = (const float*)d_in[0];
    const float* w_ih1 = (const float*)d_in[1];
    const float* w_hh1 = (const float*)d_in[2];
    const float* b1    = (const float*)d_in[3];
    const float* w_ih2 = (const float*)d_in[4];
    const float* w_hh2 = (const float*)d_in[5];
    const float* b2    = (const float*)d_in[6];
    float* out = (float*)d_out;

    hipLaunchKernelGGL(lstm_trace_kernel, dim3(256), dim3(256), 0, stream,
                       feat, w_ih1, w_hh1, b1, w_ih2, w_hh2, b2, out);
}